// Round 1
// baseline (207.301 us; speedup 1.0000x reference)
//
#include <hip/hip_runtime.h>
#include <math.h>

#define D_FEAT 128

// One edge per 16-lane group: each lane loads 8 floats (2x float4) of the
// src row and dst row, accumulates an 8-element partial dot, then a 4-step
// __shfl_xor reduction over the 16-lane group. Lane 0 writes sigmoid(dot).
__global__ __launch_bounds__(256) void edge_dot_sigmoid_kernel(
    const float* __restrict__ x,
    const int* __restrict__ ei,
    float* __restrict__ out,
    int n_edges)
{
    const int lane = threadIdx.x & 15;                   // lane within group
    const int e = blockIdx.x * 16 + (threadIdx.x >> 4);  // edge id
    if (e >= n_edges) return;

    const int s = ei[e];             // src node
    const int d = ei[n_edges + e];   // dst node

    const float4* sp = reinterpret_cast<const float4*>(x + (size_t)s * D_FEAT) + lane * 2;
    const float4* dp = reinterpret_cast<const float4*>(x + (size_t)d * D_FEAT) + lane * 2;

    float4 a0 = sp[0];
    float4 a1 = sp[1];
    float4 b0 = dp[0];
    float4 b1 = dp[1];

    float acc = a0.x * b0.x + a0.y * b0.y + a0.z * b0.z + a0.w * b0.w
              + a1.x * b1.x + a1.y * b1.y + a1.z * b1.z + a1.w * b1.w;

    // Reduce across the 16-lane group.
    acc += __shfl_xor(acc, 1, 16);
    acc += __shfl_xor(acc, 2, 16);
    acc += __shfl_xor(acc, 4, 16);
    acc += __shfl_xor(acc, 8, 16);

    if (lane == 0) {
        out[e] = 1.0f / (1.0f + __expf(-acc));
    }
}

extern "C" void kernel_launch(void* const* d_in, const int* in_sizes, int n_in,
                              void* d_out, int out_size, void* d_ws, size_t ws_size,
                              hipStream_t stream) {
    const float* x  = (const float*)d_in[0];
    const int*   ei = (const int*)d_in[1];
    float*       out = (float*)d_out;

    const int n_edges = in_sizes[1] / 2;   // edge_index is [2, E]

    const int edges_per_block = 16;        // 256 threads / 16 lanes per edge
    dim3 grid((n_edges + edges_per_block - 1) / edges_per_block);
    edge_dot_sigmoid_kernel<<<grid, 256, 0, stream>>>(x, ei, out, n_edges);
}

// Round 2
// 111.809 us; speedup vs baseline: 1.8541x; 1.8541x over previous
//
#include <hip/hip_runtime.h>
#include <hip/hip_fp16.h>
#include <math.h>

#define D_FEAT 128

// ---------------- fp32 -> fp16 conversion of x into workspace ----------------
// Each thread converts 8 floats (2x float4 load -> 8 halves -> one 16B store).
__global__ __launch_bounds__(256) void convert_x_fp16_kernel(
    const float* __restrict__ x, __half* __restrict__ xh, int n_elems)
{
    int i = blockIdx.x * blockDim.x + threadIdx.x;   // 8-element chunk id
    int base = i * 8;
    if (base >= n_elems) return;
    const float4* p = reinterpret_cast<const float4*>(x + base);
    float4 f0 = p[0];
    float4 f1 = p[1];
    __half2 h[4];
    h[0] = __floats2half2_rn(f0.x, f0.y);
    h[1] = __floats2half2_rn(f0.z, f0.w);
    h[2] = __floats2half2_rn(f1.x, f1.y);
    h[3] = __floats2half2_rn(f1.z, f1.w);
    *reinterpret_cast<float4*>(xh + base) = *reinterpret_cast<float4*>(h);
}

// ---------------- fp16 gather + dot + sigmoid ----------------
// 16-lane group per edge; fp16 row = 256B = 16 lanes x 16B (one dwordx4 each).
// Each group handles TWO edges per block so all 4 row-loads are in flight
// before any dependent math (MLP), then two 4-step shfl reductions.
struct alignas(16) h8 { __half2 h[4]; };

__device__ __forceinline__ float dot8(const h8& a, const h8& b) {
    float acc = 0.f;
#pragma unroll
    for (int k = 0; k < 4; ++k) {
        float2 fa = __half22float2(a.h[k]);
        float2 fb = __half22float2(b.h[k]);
        acc += fa.x * fb.x + fa.y * fb.y;
    }
    return acc;
}

__global__ __launch_bounds__(256) void edge_dot_sigmoid_fp16_kernel(
    const __half* __restrict__ xh,
    const int* __restrict__ ei,
    float* __restrict__ out,
    int n_edges)
{
    const int lane = threadIdx.x & 15;
    const int grp  = threadIdx.x >> 4;            // 16 groups per block
    const int base = blockIdx.x * 32;             // 32 edges per block
    const int e0 = base + grp;
    const int e1 = base + 16 + grp;

    // 1.6M edges is divisible by 32, but guard anyway.
    if (e0 >= n_edges) return;

    const int s0 = ei[e0];
    const int d0 = ei[n_edges + e0];
    const bool has1 = (e1 < n_edges);
    const int s1 = has1 ? ei[e1] : s0;
    const int d1 = has1 ? ei[n_edges + e1] : d0;

    const h8* ps0 = reinterpret_cast<const h8*>(xh + (size_t)s0 * D_FEAT) + lane;
    const h8* pd0 = reinterpret_cast<const h8*>(xh + (size_t)d0 * D_FEAT) + lane;
    const h8* ps1 = reinterpret_cast<const h8*>(xh + (size_t)s1 * D_FEAT) + lane;
    const h8* pd1 = reinterpret_cast<const h8*>(xh + (size_t)d1 * D_FEAT) + lane;

    h8 a0 = *ps0;
    h8 b0 = *pd0;
    h8 a1 = *ps1;
    h8 b1 = *pd1;

    float acc0 = dot8(a0, b0);
    float acc1 = dot8(a1, b1);

    acc0 += __shfl_xor(acc0, 1, 16);
    acc0 += __shfl_xor(acc0, 2, 16);
    acc0 += __shfl_xor(acc0, 4, 16);
    acc0 += __shfl_xor(acc0, 8, 16);

    acc1 += __shfl_xor(acc1, 1, 16);
    acc1 += __shfl_xor(acc1, 2, 16);
    acc1 += __shfl_xor(acc1, 4, 16);
    acc1 += __shfl_xor(acc1, 8, 16);

    if (lane == 0) {
        out[e0] = 1.0f / (1.0f + __expf(-acc0));
        if (has1) out[e1] = 1.0f / (1.0f + __expf(-acc1));
    }
}

// ---------------- fp32 fallback (round-1 kernel, used if ws too small) -------
__global__ __launch_bounds__(256) void edge_dot_sigmoid_fp32_kernel(
    const float* __restrict__ x,
    const int* __restrict__ ei,
    float* __restrict__ out,
    int n_edges)
{
    const int lane = threadIdx.x & 15;
    const int e = blockIdx.x * 16 + (threadIdx.x >> 4);
    if (e >= n_edges) return;

    const int s = ei[e];
    const int d = ei[n_edges + e];

    const float4* sp = reinterpret_cast<const float4*>(x + (size_t)s * D_FEAT) + lane * 2;
    const float4* dp = reinterpret_cast<const float4*>(x + (size_t)d * D_FEAT) + lane * 2;

    float4 a0 = sp[0], a1 = sp[1], b0 = dp[0], b1 = dp[1];

    float acc = a0.x * b0.x + a0.y * b0.y + a0.z * b0.z + a0.w * b0.w
              + a1.x * b1.x + a1.y * b1.y + a1.z * b1.z + a1.w * b1.w;

    acc += __shfl_xor(acc, 1, 16);
    acc += __shfl_xor(acc, 2, 16);
    acc += __shfl_xor(acc, 4, 16);
    acc += __shfl_xor(acc, 8, 16);

    if (lane == 0) out[e] = 1.0f / (1.0f + __expf(-acc));
}

extern "C" void kernel_launch(void* const* d_in, const int* in_sizes, int n_in,
                              void* d_out, int out_size, void* d_ws, size_t ws_size,
                              hipStream_t stream) {
    const float* x   = (const float*)d_in[0];
    const int*   ei  = (const int*)d_in[1];
    float*       out = (float*)d_out;

    const int n_x     = in_sizes[0];        // n_nodes * 128
    const int n_edges = in_sizes[1] / 2;    // edge_index is [2, E]

    const size_t need = (size_t)n_x * sizeof(__half);
    if (ws_size >= need) {
        __half* xh = (__half*)d_ws;
        // convert x -> fp16 (every call; deterministic)
        int n_chunks = (n_x + 7) / 8;
        convert_x_fp16_kernel<<<(n_chunks + 255) / 256, 256, 0, stream>>>(x, xh, n_x);
        // gather + dot + sigmoid
        dim3 grid((n_edges + 31) / 32);
        edge_dot_sigmoid_fp16_kernel<<<grid, 256, 0, stream>>>(xh, ei, out, n_edges);
    } else {
        dim3 grid((n_edges + 15) / 16);
        edge_dot_sigmoid_fp32_kernel<<<grid, 256, 0, stream>>>(x, ei, out, n_edges);
    }
}